// Round 6
// baseline (2336.838 us; speedup 1.0000x reference)
//
#include <hip/hip_runtime.h>

#define N_NODES 10000
#define N_CFG   16
#define N_EDGES 40000
#define CHUNK   4                 // configs per pipeline pass
#define NPC     10048             // padded nodes per config (157*64)
#define BPC     157               // 64-row blocks per config
#define UW      768               // U row: [agg 256 | x_ping 256 | x_pong 256]

typedef __attribute__((ext_vector_type(8))) short bf16x8;
typedef __attribute__((ext_vector_type(4))) float floatx4;

__device__ __forceinline__ unsigned short f2bf(float f) {
    union { float f; unsigned int u; } v; v.f = f;
    unsigned int r = (v.u + 0x7fffu + ((v.u >> 16) & 1u)) >> 16;  // RNE
    return (unsigned short)r;
}
__device__ __forceinline__ float bf2f(unsigned short h) {
    union { unsigned int u; float f; } v; v.u = ((unsigned int)h) << 16;
    return v.f;
}

// async global->LDS, 16B/lane; LDS dest MUST be wave-uniform + lane*16
__device__ __forceinline__ void gl_lds16(const unsigned short* g, unsigned short* l) {
    __builtin_amdgcn_global_load_lds(
        (const __attribute__((address_space(1))) unsigned int*)g,
        (__attribute__((address_space(3))) unsigned int*)l, 16, 0, 0);
}

// ---------------------------------------------------------------------------
// Feature build
// ---------------------------------------------------------------------------

// T[j][v][d] (bf16) = sum_t emb_layout[v][t] * lin_w[(140+4j+t)][d]
__global__ __launch_bounds__(256) void k_table(const float* __restrict__ emb_layout,
                                               const float* __restrict__ lin_w,
                                               unsigned short* __restrict__ T) {
    int b = blockIdx.x;  // 0..143
    int j = b >> 3, v = b & 7;
    int d = threadIdx.x;
    float s = 0.f;
#pragma unroll
    for (int t = 0; t < 4; ++t)
        s = fmaf(emb_layout[v * 4 + t], lin_w[(140 + 4 * j + t) * 256 + d], s);
    T[b * 256 + d] = f2bf(s);
}

// 20 nodes per block: lin_w read once per block (k-outer loop)
__global__ __launch_bounds__(256) void k_base(const float* __restrict__ x_feat,
                                              const int* __restrict__ x_op,
                                              const float* __restrict__ emb_op,
                                              const float* __restrict__ lin_w,
                                              const float* __restrict__ lin_b,
                                              unsigned short* __restrict__ base) {
    __shared__ float xf[20][144];
    const int tid = threadIdx.x;
    const int n0 = blockIdx.x * 20;
    for (int j = tid; j < 20 * 140; j += 256)
        xf[j / 140][j % 140] = x_feat[(n0 + j / 140) * 140 + (j % 140)];
    if (tid < 80) {
        int i = tid >> 2, t = tid & 3;
        xf[i][140 + t] = emb_op[x_op[n0 + i] * 4 + t];
    }
    __syncthreads();
    const int d = tid;
    float acc[20];
#pragma unroll
    for (int i = 0; i < 20; ++i) acc[i] = 0.f;
    for (int k = 0; k < 140; ++k) {
        float w = lin_w[k * 256 + d];
#pragma unroll
        for (int i = 0; i < 20; ++i) acc[i] = fmaf(xf[i][k], w, acc[i]);
    }
#pragma unroll
    for (int t = 0; t < 4; ++t) {
        float w = lin_w[(212 + t) * 256 + d];
#pragma unroll
        for (int i = 0; i < 20; ++i) acc[i] = fmaf(xf[i][140 + t], w, acc[i]);
    }
    float bb = lin_b[d];
#pragma unroll
    for (int i = 0; i < 20; ++i)
        base[(n0 + i) * 256 + d] = f2bf(acc[i] + bb);
}

// x0 -> U x_ping (cols 256..511)
__global__ __launch_bounds__(256) void k_x0(const unsigned short* __restrict__ base,
                                            const unsigned short* __restrict__ T,
                                            const int* __restrict__ cfg,
                                            unsigned short* __restrict__ U,
                                            int cc) {
    __shared__ int idx[18];
    int n = blockIdx.x, cy = blockIdx.y;
    int cg = cc * CHUNK + cy;
    int d = threadIdx.x;
    if (d < 18) idx[d] = cfg[((size_t)cg * N_NODES + n) * 18 + d];
    __syncthreads();
    float s = bf2f(base[n * 256 + d]);
#pragma unroll
    for (int j = 0; j < 18; ++j)
        s += bf2f(T[(j * 8 + idx[j]) * 256 + d]);
    U[((size_t)cy * NPC + n) * UW + 256 + d] = f2bf(s);
}

// ---------------------------------------------------------------------------
// CSR build
// ---------------------------------------------------------------------------

__global__ void k_deg(const int* __restrict__ ei, int* __restrict__ deg) {
    int e = blockIdx.x * 256 + threadIdx.x;
    if (e < N_EDGES) atomicAdd(&deg[ei[N_EDGES + e]], 1);
}

__global__ __launch_bounds__(256) void k_scan(const int* __restrict__ deg,
                                              int* __restrict__ coff) {
    __shared__ int part[257];
    int t = threadIdx.x;
    const int CH = 40;
    int start = t * CH;
    int s = 0;
    for (int i = 0; i < CH; ++i) {
        int idx = start + i;
        if (idx < N_NODES) s += deg[idx];
    }
    part[t + 1] = s;
    if (t == 0) part[0] = 0;
    __syncthreads();
    if (t == 0)
        for (int i = 1; i <= 256; ++i) part[i] += part[i - 1];
    __syncthreads();
    int run = part[t];
    for (int i = 0; i < CH; ++i) {
        int idx = start + i;
        if (idx < N_NODES) { coff[idx] = run; run += deg[idx]; }
    }
    if (t == 0) coff[N_NODES] = part[256];
}

__global__ void k_invdeg(const int* __restrict__ deg, float* __restrict__ invd) {
    int n = blockIdx.x * 256 + threadIdx.x;
    if (n < N_NODES) invd[n] = 1.0f / fmaxf((float)deg[n], 1.0f);
}

__global__ void k_fill(const int* __restrict__ ei, const int* __restrict__ coff,
                       int* __restrict__ cur, int* __restrict__ csrc) {
    int e = blockIdx.x * 256 + threadIdx.x;
    if (e < N_EDGES) {
        int d = ei[N_EDGES + e];
        int s = ei[e];
        int pos = atomicAdd(&cur[d], 1);
        csrc[coff[d] + pos] = s;
    }
}

// WT[i][n][k]: k in [0,512) = bf16_hi(Wfused[k][n]); k in [512,1024) = bf16_lo
__global__ void k_wsplit(const float* __restrict__ wl, const float* __restrict__ wr,
                         unsigned short* __restrict__ WT) {
    int t = blockIdx.x * 256 + threadIdx.x;  // < 524288
    int i = t >> 17;
    int r = (t >> 8) & 511;
    int nn = t & 255;
    float w = (r < 256) ? wl[i * 65536 + r * 256 + nn]
                        : wr[i * 65536 + (r - 256) * 256 + nn];
    unsigned short hi = f2bf(w);
    unsigned short lo = f2bf(w - bf2f(hi));
    size_t b = (size_t)i * 262144 + (size_t)nn * 1024;
    WT[b + r] = hi;
    WT[b + 512 + r] = lo;
}

// ---------------------------------------------------------------------------
// Fused agg + MFMA GEMM (+ optional mean-pool):
//   agg = mean_{in-edges} x_in  (computed into LDS, MFMA-ready swizzled)
//   x_out = relu([agg|x_in] @ (W_hi+W_lo) + bias);  pool += x_out (last layer)
// 64 rows/block, N=256 full width. LDS: Agg 32K + Bh 16K + Bl 16K = 64 KB;
// second-half x_in tiles stage into consumed Agg slots via global_load_lds.
// ---------------------------------------------------------------------------

__global__ __launch_bounds__(256) void k_fgemm(unsigned short* __restrict__ U,
                                               const unsigned short* __restrict__ WTl,
                                               const float* __restrict__ bias,
                                               const int* __restrict__ coff,
                                               const int* __restrict__ csrc,
                                               const float* __restrict__ invd,
                                               int xin, int xout,
                                               int do_pool, float* __restrict__ grow) {
    __shared__ unsigned short Agg[8 * 2048];  // 32 KB: 8 K-tiles [64][32] swizzled
    __shared__ unsigned short Bh[8192];       // 16 KB [256 n][32 k]
    __shared__ unsigned short Bl[8192];       // 16 KB
    const int tid = threadIdx.x;
    const int lane = tid & 63;
    const int wave = tid >> 6;
    const int cy = blockIdx.x / BPC;
    const int n0 = (blockIdx.x % BPC) * 64;
    const size_t r0 = (size_t)cy * NPC + n0;

    // ---- phase A: aggregate this block's 64 rows into Agg (LDS) ----
    {
        const int kt = lane >> 3;              // K-tile 0..7
        const int gt = (lane >> 1) & 3;        // granule within tile
        const int h = lane & 1;
        for (int i = 0; i < 16; ++i) {
            int rr = wave * 16 + i;            // local row 0..63
            int n = n0 + rr;
            float a0 = 0.f, a1 = 0.f, a2 = 0.f, a3 = 0.f;
            if (n < N_NODES) {
                int e0 = coff[n], e1 = coff[n + 1];
                for (int e = e0; e < e1; ++e) {
                    int s = csrc[e];
                    uint2 v = *(const uint2*)(U + ((size_t)cy * NPC + s) * UW + xin + lane * 4);
                    a0 += bf2f(v.x & 0xffff); a1 += bf2f(v.x >> 16);
                    a2 += bf2f(v.y & 0xffff); a3 += bf2f(v.y >> 16);
                }
                float iv = invd[n];
                a0 *= iv; a1 *= iv; a2 *= iv; a3 *= iv;
            }
            int gs = gt ^ ((rr >> 1) & 3);
            uint2 o;
            o.x = (unsigned int)f2bf(a0) | ((unsigned int)f2bf(a1) << 16);
            o.y = (unsigned int)f2bf(a2) | ((unsigned int)f2bf(a3) << 16);
            *(uint2*)(Agg + kt * 2048 + rr * 32 + gs * 8 + h * 4) = o;
        }
    }

    const int colg = lane & 15, kg = lane >> 4, quad = lane >> 4;
    int aoff[4], boff[4];
#pragma unroll
    for (int t = 0; t < 4; ++t) {
        int ar = t * 16 + colg;
        aoff[t] = ar * 32 + ((kg ^ ((ar >> 1) & 3)) << 3);
        int br = wave * 64 + t * 16 + colg;
        boff[t] = br * 32 + ((kg ^ ((br >> 1) & 3)) << 3);
    }

    floatx4 acc[4][4];
#pragma unroll
    for (int i = 0; i < 4; ++i)
#pragma unroll
        for (int j = 0; j < 4; ++j) acc[i][j] = (floatx4){0.f, 0.f, 0.f, 0.f};

    const int srow = tid >> 2;                     // staged row 0..63
    const int gc = (tid & 3) ^ ((srow >> 1) & 3);  // fetched k-granule (swizzle)
    const unsigned short* Arow = U + (r0 + srow) * UW + gc * 8;
    const unsigned short* Wrow = WTl + (size_t)srow * 1024 + gc * 8;

    __syncthreads();  // phase A complete; Agg tiles 0..7 valid

    for (int kt8 = 0; kt8 < 16; ++kt8) {
        const int kt = kt8 * 32;
        if (kt8 >= 8)  // stage x_in tile into the consumed Agg slot
            gl_lds16(Arow + (xin + kt - 256), Agg + (kt8 - 8) * 2048 + tid * 8);
#pragma unroll
        for (int q = 0; q < 4; ++q) {
            gl_lds16(Wrow + (size_t)q * 65536 + kt,       Bh + q * 2048 + tid * 8);
            gl_lds16(Wrow + (size_t)q * 65536 + 512 + kt, Bl + q * 2048 + tid * 8);
        }
        __syncthreads();  // drains vmcnt -> staged data visible

        const unsigned short* At = Agg + ((kt8 < 8) ? kt8 : (kt8 - 8)) * 2048;
        bf16x8 a[4], bh[4], bl[4];
#pragma unroll
        for (int t = 0; t < 4; ++t) a[t] = *(const bf16x8*)(At + aoff[t]);
#pragma unroll
        for (int t = 0; t < 4; ++t) {
            bh[t] = *(const bf16x8*)(Bh + boff[t]);
            bl[t] = *(const bf16x8*)(Bl + boff[t]);
        }
#pragma unroll
        for (int ti = 0; ti < 4; ++ti)
#pragma unroll
            for (int tj = 0; tj < 4; ++tj)
                acc[ti][tj] = __builtin_amdgcn_mfma_f32_16x16x32_bf16(
                    a[ti], bh[tj], acc[ti][tj], 0, 0, 0);
#pragma unroll
        for (int ti = 0; ti < 4; ++ti)
#pragma unroll
            for (int tj = 0; tj < 4; ++tj)
                acc[ti][tj] = __builtin_amdgcn_mfma_f32_16x16x32_bf16(
                    a[ti], bl[tj], acc[ti][tj], 0, 0, 0);
        __syncthreads();  // all waves done with LDS before restage
    }

#pragma unroll
    for (int tj = 0; tj < 4; ++tj) {
        int nn = wave * 64 + tj * 16 + colg;
        float bv = bias[nn];
        float psum = 0.f;
#pragma unroll
        for (int ti = 0; ti < 4; ++ti) {
#pragma unroll
            for (int r = 0; r < 4; ++r) {
                int rloc = ti * 16 + quad * 4 + r;
                float y = acc[ti][tj][r] + bv;
                unsigned short yb = f2bf(fmaxf(y, 0.f));
                if (n0 + rloc < N_NODES) {
                    U[(r0 + rloc) * UW + xout + nn] = yb;
                    psum += bf2f(yb);
                }
            }
        }
        if (do_pool) {
            psum += __shfl_xor(psum, 16, 64);
            psum += __shfl_xor(psum, 32, 64);
            if (quad == 0) atomicAdd(&grow[cy * 256 + nn], psum);
        }
    }
}

// ---------------------------------------------------------------------------
// Head
// ---------------------------------------------------------------------------

__global__ __launch_bounds__(256) void k_head(const float* __restrict__ g,
                                              const float* __restrict__ w1,
                                              const float* __restrict__ b1,
                                              const float* __restrict__ w2,
                                              const float* __restrict__ b2,
                                              const float* __restrict__ w3,
                                              const float* __restrict__ b3,
                                              float* __restrict__ out) {
    __shared__ float ha[256];
    __shared__ float hb[256];
    __shared__ float red[4];
    int c = blockIdx.x;
    int d = threadIdx.x;
    ha[d] = g[c * 256 + d] / 10000.0f;
    __syncthreads();
    float s = b1[d];
#pragma unroll 4
    for (int k = 0; k < 256; ++k)
        s = fmaf(ha[k], w1[k * 256 + d], s);
    hb[d] = fmaxf(s, 0.f);
    __syncthreads();
    s = b2[d];
#pragma unroll 4
    for (int k = 0; k < 256; ++k)
        s = fmaf(hb[k], w2[k * 256 + d], s);
    ha[d] = fmaxf(s, 0.f);
    __syncthreads();
    float p = ha[d] * w3[d];
#pragma unroll
    for (int off = 32; off > 0; off >>= 1)
        p += __shfl_down(p, off, 64);
    if ((d & 63) == 0) red[d >> 6] = p;
    __syncthreads();
    if (d == 0)
        out[c] = red[0] + red[1] + red[2] + red[3] + b3[0];
}

__global__ void k_wsfail(float* __restrict__ out, float v) {
    out[threadIdx.x] = v;
}

// ---------------------------------------------------------------------------

extern "C" void kernel_launch(void* const* d_in, const int* in_sizes, int n_in,
                              void* d_out, int out_size, void* d_ws, size_t ws_size,
                              hipStream_t stream) {
    const int*   x_node_cfg = (const int*)  d_in[0];
    const float* x_feat     = (const float*)d_in[1];
    const int*   x_op       = (const int*)  d_in[2];
    const int*   edge_index = (const int*)  d_in[3];
    const float* emb_op     = (const float*)d_in[4];
    const float* emb_layout = (const float*)d_in[5];
    const float* lin_w      = (const float*)d_in[6];
    const float* lin_b      = (const float*)d_in[7];
    const float* conv_wl    = (const float*)d_in[8];
    const float* conv_bl    = (const float*)d_in[9];
    const float* conv_wr    = (const float*)d_in[10];
    const float* w1         = (const float*)d_in[11];
    const float* b1         = (const float*)d_in[12];
    const float* w2         = (const float*)d_in[13];
    const float* b2         = (const float*)d_in[14];
    const float* w3         = (const float*)d_in[15];
    const float* b3         = (const float*)d_in[16];
    float* out = (float*)d_out;

    // workspace layout — NEED = 71,459,332 bytes (< 74.36 MB known-good)
    unsigned short* U    = (unsigned short*)d_ws;       // [4*10048][768]
    unsigned short* base = U + (size_t)4 * NPC * UW;    // [10000][256]
    unsigned short* T    = base + 2560000;              // [18][8][256]
    unsigned short* WT   = T + 36864;                   // [4][256][1024]
    float* invd = (float*)(WT + 1048576);               // [10000]
    float* g    = invd + 10000;                         // [16][256] pad 4096
    int* deg  = (int*)(g + 4096);                       // [10000]
    int* coff = deg + 10000;                            // [10001]
    int* cur  = coff + 10001;                           // [10000]
    int* csrc = cur + 10000;                            // [40000]

    const size_t NEED = 71459332;
    if (ws_size < NEED) {
        k_wsfail<<<1, 16, 0, stream>>>(out, (float)ws_size * 1e-9f);
        return;
    }

    hipMemsetAsync(deg, 0, N_NODES * sizeof(int), stream);
    hipMemsetAsync(cur, 0, N_NODES * sizeof(int), stream);
    hipMemsetAsync(g, 0, 4096 * sizeof(float), stream);

    k_table<<<144, 256, 0, stream>>>(emb_layout, lin_w, T);
    k_base<<<500, 256, 0, stream>>>(x_feat, x_op, emb_op, lin_w, lin_b, base);
    k_deg<<<(N_EDGES + 255) / 256, 256, 0, stream>>>(edge_index, deg);
    k_scan<<<1, 256, 0, stream>>>(deg, coff);
    k_invdeg<<<(N_NODES + 255) / 256, 256, 0, stream>>>(deg, invd);
    k_fill<<<(N_EDGES + 255) / 256, 256, 0, stream>>>(edge_index, coff, cur, csrc);
    k_wsplit<<<2048, 256, 0, stream>>>(conv_wl, conv_wr, WT);

    for (int cc = 0; cc < N_CFG / CHUNK; ++cc) {
        k_x0<<<dim3(N_NODES, CHUNK), 256, 0, stream>>>(base, T, x_node_cfg, U, cc);
        for (int i = 0; i < 4; ++i) {
            int xin = (i & 1) ? 512 : 256;
            int xout = (i & 1) ? 256 : 512;
            k_fgemm<<<CHUNK * BPC, 256, 0, stream>>>(
                U, WT + i * 262144, conv_bl + i * 256, coff, csrc, invd,
                xin, xout, (i == 3) ? 1 : 0, g + cc * CHUNK * 256);
        }
    }

    k_head<<<16, 256, 0, stream>>>(g, w1, b1, w2, b2, w3, b3, out);
}

// Round 7
// 1211.316 us; speedup vs baseline: 1.9292x; 1.9292x over previous
//
#include <hip/hip_runtime.h>

#define N_NODES 10000
#define N_CFG   16
#define N_EDGES 40000
#define UW      512               // U row: [agg 256 | x 256] (x updated in-place)

typedef __attribute__((ext_vector_type(8))) short bf16x8;
typedef __attribute__((ext_vector_type(4))) float floatx4;

__device__ __forceinline__ unsigned short f2bf(float f) {
    union { float f; unsigned int u; } v; v.f = f;
    unsigned int r = (v.u + 0x7fffu + ((v.u >> 16) & 1u)) >> 16;  // RNE
    return (unsigned short)r;
}
__device__ __forceinline__ float bf2f(unsigned short h) {
    union { unsigned int u; float f; } v; v.u = ((unsigned int)h) << 16;
    return v.f;
}

// async global->LDS, 16B/lane; LDS dest MUST be wave-uniform + lane*16
__device__ __forceinline__ void gl_lds16(const unsigned short* g, unsigned short* l) {
    __builtin_amdgcn_global_load_lds(
        (const __attribute__((address_space(1))) unsigned int*)g,
        (__attribute__((address_space(3))) unsigned int*)l, 16, 0, 0);
}

// ---------------------------------------------------------------------------
// Feature build
// ---------------------------------------------------------------------------

__global__ __launch_bounds__(256) void k_table(const float* __restrict__ emb_layout,
                                               const float* __restrict__ lin_w,
                                               unsigned short* __restrict__ T) {
    int b = blockIdx.x;  // 0..143
    int j = b >> 3, v = b & 7;
    int d = threadIdx.x;
    float s = 0.f;
#pragma unroll
    for (int t = 0; t < 4; ++t)
        s = fmaf(emb_layout[v * 4 + t], lin_w[(140 + 4 * j + t) * 256 + d], s);
    T[b * 256 + d] = f2bf(s);
}

// 20 nodes per block: lin_w read once per block (k-outer loop)
__global__ __launch_bounds__(256) void k_base(const float* __restrict__ x_feat,
                                              const int* __restrict__ x_op,
                                              const float* __restrict__ emb_op,
                                              const float* __restrict__ lin_w,
                                              const float* __restrict__ lin_b,
                                              unsigned short* __restrict__ base) {
    __shared__ float xf[20][144];
    const int tid = threadIdx.x;
    const int n0 = blockIdx.x * 20;
    for (int j = tid; j < 20 * 140; j += 256)
        xf[j / 140][j % 140] = x_feat[(n0 + j / 140) * 140 + (j % 140)];
    if (tid < 80) {
        int i = tid >> 2, t = tid & 3;
        xf[i][140 + t] = emb_op[x_op[n0 + i] * 4 + t];
    }
    __syncthreads();
    const int d = tid;
    float acc[20];
#pragma unroll
    for (int i = 0; i < 20; ++i) acc[i] = 0.f;
    for (int k = 0; k < 140; ++k) {
        float w = lin_w[k * 256 + d];
#pragma unroll
        for (int i = 0; i < 20; ++i) acc[i] = fmaf(xf[i][k], w, acc[i]);
    }
#pragma unroll
    for (int t = 0; t < 4; ++t) {
        float w = lin_w[(212 + t) * 256 + d];
#pragma unroll
        for (int i = 0; i < 20; ++i) acc[i] = fmaf(xf[i][140 + t], w, acc[i]);
    }
    float bb = lin_b[d];
#pragma unroll
    for (int i = 0; i < 20; ++i)
        base[(n0 + i) * 256 + d] = f2bf(acc[i] + bb);
}

// x0 -> U x cols (256..511)
template <int CH>
__global__ __launch_bounds__(256) void k_x0(const unsigned short* __restrict__ base,
                                            const unsigned short* __restrict__ T,
                                            const int* __restrict__ cfg,
                                            unsigned short* __restrict__ U,
                                            int cc) {
    __shared__ int idx[18];
    int n = blockIdx.x, cy = blockIdx.y;
    int cg = cc * CH + cy;
    int d = threadIdx.x;
    if (d < 18) idx[d] = cfg[((size_t)cg * N_NODES + n) * 18 + d];
    __syncthreads();
    float s = bf2f(base[n * 256 + d]);
#pragma unroll
    for (int j = 0; j < 18; ++j)
        s += bf2f(T[(j * 8 + idx[j]) * 256 + d]);
    U[((size_t)cy * N_NODES + n) * UW + 256 + d] = f2bf(s);
}

// ---------------------------------------------------------------------------
// CSR build
// ---------------------------------------------------------------------------

__global__ void k_deg(const int* __restrict__ ei, int* __restrict__ deg) {
    int e = blockIdx.x * 256 + threadIdx.x;
    if (e < N_EDGES) atomicAdd(&deg[ei[N_EDGES + e]], 1);
}

__global__ __launch_bounds__(256) void k_scan(const int* __restrict__ deg,
                                              int* __restrict__ coff) {
    __shared__ int part[257];
    int t = threadIdx.x;
    const int CHk = 40;
    int start = t * CHk;
    int s = 0;
    for (int i = 0; i < CHk; ++i) {
        int idx = start + i;
        if (idx < N_NODES) s += deg[idx];
    }
    part[t + 1] = s;
    if (t == 0) part[0] = 0;
    __syncthreads();
    if (t == 0)
        for (int i = 1; i <= 256; ++i) part[i] += part[i - 1];
    __syncthreads();
    int run = part[t];
    for (int i = 0; i < CHk; ++i) {
        int idx = start + i;
        if (idx < N_NODES) { coff[idx] = run; run += deg[idx]; }
    }
    if (t == 0) coff[N_NODES] = part[256];
}

__global__ void k_invdeg(const int* __restrict__ deg, float* __restrict__ invd) {
    int n = blockIdx.x * 256 + threadIdx.x;
    if (n < N_NODES) invd[n] = 1.0f / fmaxf((float)deg[n], 1.0f);
}

__global__ void k_fill(const int* __restrict__ ei, const int* __restrict__ coff,
                       int* __restrict__ cur, int* __restrict__ csrc) {
    int e = blockIdx.x * 256 + threadIdx.x;
    if (e < N_EDGES) {
        int d = ei[N_EDGES + e];
        int s = ei[e];
        int pos = atomicAdd(&cur[d], 1);
        csrc[coff[d] + pos] = s;
    }
}

// WT[i][n][k]: k in [0,512) = bf16_hi(Wfused[k][n]); k in [512,1024) = bf16_lo
__global__ void k_wsplit(const float* __restrict__ wl, const float* __restrict__ wr,
                         unsigned short* __restrict__ WT) {
    int t = blockIdx.x * 256 + threadIdx.x;  // < 524288
    int i = t >> 17;
    int r = (t >> 8) & 511;
    int nn = t & 255;
    float w = (r < 256) ? wl[i * 65536 + r * 256 + nn]
                        : wr[i * 65536 + (r - 256) * 256 + nn];
    unsigned short hi = f2bf(w);
    unsigned short lo = f2bf(w - bf2f(hi));
    size_t b = (size_t)i * 262144 + (size_t)nn * 1024;
    WT[b + r] = hi;
    WT[b + 512 + r] = lo;
}

// ---------------------------------------------------------------------------
// Aggregation: one wave per node, all CH configs (CH independent gathers/edge)
// ---------------------------------------------------------------------------

template <int CH>
__global__ __launch_bounds__(256) void k_agg(unsigned short* __restrict__ U,
                                             const int* __restrict__ coff,
                                             const int* __restrict__ csrc,
                                             const float* __restrict__ invd) {
    int wave = threadIdx.x >> 6, lane = threadIdx.x & 63;
    int n = blockIdx.x * 4 + wave;
    int e0 = coff[n], e1 = coff[n + 1];
    float acc[CH][4];
#pragma unroll
    for (int cy = 0; cy < CH; ++cy)
#pragma unroll
        for (int j = 0; j < 4; ++j) acc[cy][j] = 0.f;
    for (int e = e0; e < e1; ++e) {
        int s = csrc[e];
        const unsigned short* p = U + (size_t)s * UW + 256 + lane * 4;
#pragma unroll
        for (int cy = 0; cy < CH; ++cy) {
            uint2 v = *(const uint2*)(p + (size_t)cy * N_NODES * UW);
            acc[cy][0] += bf2f(v.x & 0xffff);
            acc[cy][1] += bf2f(v.x >> 16);
            acc[cy][2] += bf2f(v.y & 0xffff);
            acc[cy][3] += bf2f(v.y >> 16);
        }
    }
    float iv = invd[n];
#pragma unroll
    for (int cy = 0; cy < CH; ++cy) {
        uint2 o;
        o.x = (unsigned int)f2bf(acc[cy][0] * iv) |
              ((unsigned int)f2bf(acc[cy][1] * iv) << 16);
        o.y = (unsigned int)f2bf(acc[cy][2] * iv) |
              ((unsigned int)f2bf(acc[cy][3] * iv) << 16);
        *(uint2*)(U + ((size_t)cy * N_NODES + n) * UW + lane * 4) = o;
    }
}

// ---------------------------------------------------------------------------
// MFMA GEMM: x = relu( [agg|x] @ (W_hi + W_lo) + bias ), in place.
// BM=64, BN=256; 16 K-tiles of 32 over U's contiguous 512 cols (no branch);
// global_load_lds staging (no prefetch VGPRs), 36 KB LDS, XOR swizzle
// (0 conflicts measured r3/r4/r5). Safe in place: block reads only its own
// 64 rows; x writes happen after the last K-tile is consumed.
// ---------------------------------------------------------------------------

__global__ __launch_bounds__(256) void k_gemm(unsigned short* __restrict__ U,
                                              const unsigned short* __restrict__ WTl,
                                              const float* __restrict__ bias) {
    __shared__ unsigned short Asm[64 * 32];    // 4 KB
    __shared__ unsigned short Bh[256 * 32];    // 16 KB
    __shared__ unsigned short Bl[256 * 32];    // 16 KB
    const int tid = threadIdx.x;
    const int lane = tid & 63;
    const int wave = tid >> 6;                 // n-slice: wave*64
    const size_t r0 = (size_t)blockIdx.x * 64;

    const int srow = tid >> 2;                     // staged row 0..63
    const int gc = (tid & 3) ^ ((srow >> 1) & 3);  // fetched k-granule (swizzle)

    const int colg = lane & 15, kg = lane >> 4, quad = lane >> 4;
    int aoff[4], boff[4];
#pragma unroll
    for (int t = 0; t < 4; ++t) {
        int ar = t * 16 + colg;
        aoff[t] = ar * 32 + ((kg ^ ((ar >> 1) & 3)) << 3);
        int br = wave * 64 + t * 16 + colg;
        boff[t] = br * 32 + ((kg ^ ((br >> 1) & 3)) << 3);
    }

    floatx4 acc[4][4];
#pragma unroll
    for (int i = 0; i < 4; ++i)
#pragma unroll
        for (int j = 0; j < 4; ++j) acc[i][j] = (floatx4){0.f, 0.f, 0.f, 0.f};

    const unsigned short* Arow = U + (r0 + srow) * UW + gc * 8;
    const unsigned short* Wrow = WTl + (size_t)srow * 1024 + gc * 8;

    for (int kt = 0; kt < 512; kt += 32) {
        gl_lds16(Arow + kt, Asm + tid * 8);
#pragma unroll
        for (int q = 0; q < 4; ++q) {
            gl_lds16(Wrow + (size_t)q * 65536 + kt,       Bh + q * 2048 + tid * 8);
            gl_lds16(Wrow + (size_t)q * 65536 + 512 + kt, Bl + q * 2048 + tid * 8);
        }
        __syncthreads();  // drains vmcnt -> staged data visible

        bf16x8 a[4], bh[4], bl[4];
#pragma unroll
        for (int t = 0; t < 4; ++t) a[t] = *(const bf16x8*)(Asm + aoff[t]);
#pragma unroll
        for (int t = 0; t < 4; ++t) {
            bh[t] = *(const bf16x8*)(Bh + boff[t]);
            bl[t] = *(const bf16x8*)(Bl + boff[t]);
        }
#pragma unroll
        for (int ti = 0; ti < 4; ++ti)
#pragma unroll
            for (int tj = 0; tj < 4; ++tj)
                acc[ti][tj] = __builtin_amdgcn_mfma_f32_16x16x32_bf16(
                    a[ti], bh[tj], acc[ti][tj], 0, 0, 0);
#pragma unroll
        for (int ti = 0; ti < 4; ++ti)
#pragma unroll
            for (int tj = 0; tj < 4; ++tj)
                acc[ti][tj] = __builtin_amdgcn_mfma_f32_16x16x32_bf16(
                    a[ti], bl[tj], acc[ti][tj], 0, 0, 0);
        __syncthreads();  // all waves done with LDS before restage
    }

#pragma unroll
    for (int tj = 0; tj < 4; ++tj) {
        int nn = wave * 64 + tj * 16 + colg;
        float bv = bias[nn];
#pragma unroll
        for (int ti = 0; ti < 4; ++ti) {
#pragma unroll
            for (int r = 0; r < 4; ++r) {
                size_t mm = r0 + (size_t)(ti * 16 + quad * 4 + r);
                float y = acc[ti][tj][r] + bv;
                U[mm * UW + 256 + nn] = f2bf(fmaxf(y, 0.f));
            }
        }
    }
}

// ---------------------------------------------------------------------------
// Pool + head
// ---------------------------------------------------------------------------

template <int CH>
__global__ __launch_bounds__(256) void k_pool(const unsigned short* __restrict__ U,
                                              float* __restrict__ g, int cc) {
    int cy = blockIdx.y;
    int d = threadIdx.x;
    size_t row0 = (size_t)cy * N_NODES + blockIdx.x * 250;
    float s = 0.f;
    for (int i = 0; i < 250; ++i)
        s += bf2f(U[(row0 + i) * UW + 256 + d]);
    atomicAdd(&g[(cc * CH + cy) * 256 + d], s);
}

__global__ __launch_bounds__(256) void k_head(const float* __restrict__ g,
                                              const float* __restrict__ w1,
                                              const float* __restrict__ b1,
                                              const float* __restrict__ w2,
                                              const float* __restrict__ b2,
                                              const float* __restrict__ w3,
                                              const float* __restrict__ b3,
                                              float* __restrict__ out) {
    __shared__ float ha[256];
    __shared__ float hb[256];
    __shared__ float red[4];
    int c = blockIdx.x;
    int d = threadIdx.x;
    ha[d] = g[c * 256 + d] / 10000.0f;
    __syncthreads();
    float s = b1[d];
#pragma unroll 4
    for (int k = 0; k < 256; ++k)
        s = fmaf(ha[k], w1[k * 256 + d], s);
    hb[d] = fmaxf(s, 0.f);
    __syncthreads();
    s = b2[d];
#pragma unroll 4
    for (int k = 0; k < 256; ++k)
        s = fmaf(hb[k], w2[k * 256 + d], s);
    ha[d] = fmaxf(s, 0.f);
    __syncthreads();
    float p = ha[d] * w3[d];
#pragma unroll
    for (int off = 32; off > 0; off >>= 1)
        p += __shfl_down(p, off, 64);
    if ((d & 63) == 0) red[d >> 6] = p;
    __syncthreads();
    if (d == 0)
        out[c] = red[0] + red[1] + red[2] + red[3] + b3[0];
}

__global__ void k_wsfail(float* __restrict__ out, float v) {
    out[threadIdx.x] = v;
}

// ---------------------------------------------------------------------------

extern "C" void kernel_launch(void* const* d_in, const int* in_sizes, int n_in,
                              void* d_out, int out_size, void* d_ws, size_t ws_size,
                              hipStream_t stream) {
    const int*   x_node_cfg = (const int*)  d_in[0];
    const float* x_feat     = (const float*)d_in[1];
    const int*   x_op       = (const int*)  d_in[2];
    const int*   edge_index = (const int*)  d_in[3];
    const float* emb_op     = (const float*)d_in[4];
    const float* emb_layout = (const float*)d_in[5];
    const float* lin_w      = (const float*)d_in[6];
    const float* lin_b      = (const float*)d_in[7];
    const float* conv_wl    = (const float*)d_in[8];
    const float* conv_bl    = (const float*)d_in[9];
    const float* conv_wr    = (const float*)d_in[10];
    const float* w1         = (const float*)d_in[11];
    const float* b1         = (const float*)d_in[12];
    const float* w2         = (const float*)d_in[13];
    const float* b2         = (const float*)d_in[14];
    const float* w3         = (const float*)d_in[15];
    const float* b3         = (const float*)d_in[16];
    float* out = (float*)d_out;

    // rest-of-workspace = 7,627,268 B; U = CH*10000*512*2 B
    const size_t NEED8  = (size_t)8  * N_NODES * UW * 2 + 7627268;  //  89.5 MB
    const size_t NEED16 = (size_t)16 * N_NODES * UW * 2 + 7627268;  // 171.5 MB
    const int CH = (ws_size >= NEED16) ? 16 : 8;

    unsigned short* U    = (unsigned short*)d_ws;          // [CH*10000][512]
    unsigned short* base = U + (size_t)CH * N_NODES * UW;  // [10000][256]
    unsigned short* T    = base + 2560000;                 // [18][8][256]
    unsigned short* WT   = T + 36864;                      // [4][256][1024]
    float* invd = (float*)(WT + 1048576);                  // [10000]
    float* g    = invd + 10000;                            // [16][256] pad 4096
    int* deg  = (int*)(g + 4096);                          // [10000]
    int* coff = deg + 10000;                               // [10001]
    int* cur  = coff + 10001;                              // [10000]
    int* csrc = cur + 10000;                               // [40000]

    if (ws_size < NEED8) {
        k_wsfail<<<1, 16, 0, stream>>>(out, (float)ws_size * 1e-9f);
        return;
    }

    hipMemsetAsync(deg, 0, N_NODES * sizeof(int), stream);
    hipMemsetAsync(cur, 0, N_NODES * sizeof(int), stream);
    hipMemsetAsync(g, 0, 4096 * sizeof(float), stream);

    k_table<<<144, 256, 0, stream>>>(emb_layout, lin_w, T);
    k_base<<<500, 256, 0, stream>>>(x_feat, x_op, emb_op, lin_w, lin_b, base);
    k_deg<<<(N_EDGES + 255) / 256, 256, 0, stream>>>(edge_index, deg);
    k_scan<<<1, 256, 0, stream>>>(deg, coff);
    k_invdeg<<<(N_NODES + 255) / 256, 256, 0, stream>>>(deg, invd);
    k_fill<<<(N_EDGES + 255) / 256, 256, 0, stream>>>(edge_index, coff, cur, csrc);
    k_wsplit<<<2048, 256, 0, stream>>>(conv_wl, conv_wr, WT);

    if (CH == 16) {
        k_x0<16><<<dim3(N_NODES, 16), 256, 0, stream>>>(base, T, x_node_cfg, U, 0);
        for (int i = 0; i < 4; ++i) {
            k_agg<16><<<2500, 256, 0, stream>>>(U, coff, csrc, invd);
            k_gemm<<<16 * N_NODES / 64, 256, 0, stream>>>(U, WT + i * 262144,
                                                          conv_bl + i * 256);
        }
        k_pool<16><<<dim3(40, 16), 256, 0, stream>>>(U, g, 0);
    } else {
        for (int cc = 0; cc < 2; ++cc) {
            k_x0<8><<<dim3(N_NODES, 8), 256, 0, stream>>>(base, T, x_node_cfg, U, cc);
            for (int i = 0; i < 4; ++i) {
                k_agg<8><<<2500, 256, 0, stream>>>(U, coff, csrc, invd);
                k_gemm<<<8 * N_NODES / 64, 256, 0, stream>>>(U, WT + i * 262144,
                                                             conv_bl + i * 256);
            }
            k_pool<8><<<dim3(40, 8), 256, 0, stream>>>(U, g, cc);
        }
    }

    k_head<<<16, 256, 0, stream>>>(g, w1, b1, w2, b2, w3, b3, out);
}